// Round 6
// baseline (546.382 us; speedup 1.0000x reference)
//
#include <hip/hip_runtime.h>
#include <cmath>

#define DIM 1024
#define DIM_INNER 2048
#define BATCH 4
#define SEQ 4096
#define MTOT (BATCH * SEQ)
#define CHUNK 64
#define NCHUNK (SEQ / CHUNK)        // 64 chunks per sequence

typedef __bf16 bf16x8 __attribute__((ext_vector_type(8)));
typedef short short8_t __attribute__((ext_vector_type(8)));
typedef float floatx4 __attribute__((ext_vector_type(4)));
typedef unsigned short u16x4 __attribute__((ext_vector_type(4)));
typedef unsigned short ushort_t;

__device__ __forceinline__ unsigned short f2bf(float f) {
  unsigned int u = __builtin_bit_cast(unsigned int, f);
  u += 0x7fffu + ((u >> 16) & 1u);   // round-to-nearest-even
  return (unsigned short)(u >> 16);
}
__device__ __forceinline__ float bflo2f(unsigned int u) {
  return __builtin_bit_cast(float, u << 16);
}
__device__ __forceinline__ float bfhi2f(unsigned int u) {
  return __builtin_bit_cast(float, u & 0xffff0000u);
}

// Fast (native v_exp/v_log) log-space terms from (h, g):
//   lc = -softplus(g) ;  lv = -softplus(-g) + log_g(h) = g + lc + log_g(h)
__device__ __forceinline__ void lclv_fast(float h, float g, float& lc, float& lv) {
  float eg = __expf(-fabsf(g));
  float sp = fmaxf(g, 0.f) + __logf(1.f + eg);
  lc = -sp;
  float eh = __expf(h);
  float t  = (h >= 0.f) ? (h + 0.5f) : (1.f + eh);
  float lt = __logf(t);
  float lg = (h >= 0.f) ? lt : (h - lt);
  lv = g + lc + lg;
}
// a may be -inf; b finite
__device__ __forceinline__ float logaddexp_f(float a, float b) {
  float m = fmaxf(a, b);
  return m + __logf(1.f + __expf(-fabsf(a - b)));
}

// async 16B/lane global->LDS; dest = wave-uniform base + lane*16
__device__ __forceinline__ void async_copy16(const ushort_t* g, ushort_t* l) {
  __builtin_amdgcn_global_load_lds(
      (const __attribute__((address_space(1))) void*)g,
      (__attribute__((address_space(3))) void*)l, 16, 0, 0);
}

// ---------------------------------------------------------------------------
// One-time input conversions
// ---------------------------------------------------------------------------
__global__ __launch_bounds__(256) void convert_f32_bf16(
    const float* __restrict__ src, ushort_t* __restrict__ dst) {
  int i = blockIdx.x * 256 + threadIdx.x;   // one float4 per thread
  float4 v = ((const float4*)src)[i];
  u16x4 o = {f2bf(v.x), f2bf(v.y), f2bf(v.z), f2bf(v.w)};
  ((u16x4*)dst)[i] = o;
}

// dst[n][k] = bf16(src[k][n]); src is [K][N] fp32
__global__ __launch_bounds__(256) void transpose_f32_bf16(
    const float* __restrict__ src, ushort_t* __restrict__ dst, int K, int N) {
  __shared__ float tile[32][33];
  int tx = threadIdx.x & 31, ty = threadIdx.x >> 5;   // 32 x 8
  int n0 = blockIdx.x * 32, k0 = blockIdx.y * 32;
#pragma unroll
  for (int i = 0; i < 4; i++) {
    int k = ty + i * 8;
    tile[k][tx] = src[(size_t)(k0 + k) * N + n0 + tx];
  }
  __syncthreads();
#pragma unroll
  for (int i = 0; i < 4; i++) {
    int r = ty + i * 8;
    dst[(size_t)(n0 + r) * K + k0 + tx] = f2bf(tile[tx][r]);
  }
}

// ---------------------------------------------------------------------------
// GEMM1 fused: per block a 128x64 h-tile + 128x64 g-tile (shared A tile).
// Epilogue packs (h,g) as 2xbf16 -> HG; transcendentals live in the scans.
// ---------------------------------------------------------------------------
__global__ __launch_bounds__(256) void gemm1_fused(
    const ushort_t* __restrict__ Xbf, const ushort_t* __restrict__ Wt,
    unsigned int* __restrict__ HG) {
  __shared__ __align__(16) ushort_t As[128 * 32];   // 8 KB
  __shared__ __align__(16) ushort_t Bh[64 * 32];    // 4 KB
  __shared__ __align__(16) ushort_t Bg[64 * 32];    // 4 KB

  const int tid = threadIdx.x;
  const int wave = tid >> 6;
  const int lane = tid & 63;
  const int n0 = blockIdx.x * 64;
  const int m0 = blockIdx.y * 128;
  const int l15 = lane & 15;
  const int quad = lane >> 4;
  const int wr = wave >> 1, wc = wave & 1;
  const int lrow = lane >> 2;
  const int lkof = (lane & 3) * 8;

  floatx4 acch[4][2], accg[4][2];
#pragma unroll
  for (int i = 0; i < 4; i++)
#pragma unroll
    for (int j = 0; j < 2; j++) {
      acch[i][j] = (floatx4){0.f, 0.f, 0.f, 0.f};
      accg[i][j] = (floatx4){0.f, 0.f, 0.f, 0.f};
    }

  for (int k0 = 0; k0 < DIM; k0 += 32) {
    __syncthreads();
    async_copy16(Xbf + (size_t)(m0 + wave * 16 + lrow) * DIM + k0 + lkof,
                 As + wave * 512);
    async_copy16(Xbf + (size_t)(m0 + (wave + 4) * 16 + lrow) * DIM + k0 + lkof,
                 As + (wave + 4) * 512);
    async_copy16(Wt + (size_t)(n0 + wave * 16 + lrow) * DIM + k0 + lkof,
                 Bh + wave * 512);
    async_copy16(Wt + (size_t)(n0 + DIM_INNER + wave * 16 + lrow) * DIM + k0 + lkof,
                 Bg + wave * 512);
    __syncthreads();

    bf16x8 af[4], bhf[2], bgf[2];
#pragma unroll
    for (int i = 0; i < 4; i++) {
      short8_t sa = *(const short8_t*)(As + (size_t)(wr * 64 + i * 16 + l15) * 32 + quad * 8);
      af[i] = __builtin_bit_cast(bf16x8, sa);
    }
#pragma unroll
    for (int j = 0; j < 2; j++) {
      short8_t sh = *(const short8_t*)(Bh + (size_t)(wc * 32 + j * 16 + l15) * 32 + quad * 8);
      bhf[j] = __builtin_bit_cast(bf16x8, sh);
      short8_t sg = *(const short8_t*)(Bg + (size_t)(wc * 32 + j * 16 + l15) * 32 + quad * 8);
      bgf[j] = __builtin_bit_cast(bf16x8, sg);
    }
#pragma unroll
    for (int i = 0; i < 4; i++)
#pragma unroll
      for (int j = 0; j < 2; j++) {
        acch[i][j] = __builtin_amdgcn_mfma_f32_16x16x32_bf16(af[i], bhf[j], acch[i][j], 0, 0, 0);
        accg[i][j] = __builtin_amdgcn_mfma_f32_16x16x32_bf16(af[i], bgf[j], accg[i][j], 0, 0, 0);
      }
  }

#pragma unroll
  for (int i = 0; i < 4; i++)
#pragma unroll
    for (int j = 0; j < 2; j++) {
      int col = n0 + wc * 32 + j * 16 + l15;
#pragma unroll
      for (int r = 0; r < 4; r++) {
        int row = m0 + wr * 64 + i * 16 + quad * 4 + r;
        unsigned int pk = ((unsigned int)f2bf(accg[i][j][r]) << 16) |
                          (unsigned int)f2bf(acch[i][j][r]);
        HG[(size_t)row * DIM_INNER + col] = pk;
      }
    }
}

// ---------------------------------------------------------------------------
// Chunked log-space scan, 4 channels per thread (uint4 loads, 4 indep chains)
// ---------------------------------------------------------------------------
typedef unsigned int uint4_t __attribute__((ext_vector_type(4)));
typedef float float4_t __attribute__((ext_vector_type(4)));

__global__ __launch_bounds__(256) void scan_phase1(
    const unsigned int* __restrict__ HG,
    float* __restrict__ Asum, float* __restrict__ Lend, int nbch) {
  const int EQ = DIM_INNER / 4;               // 512 channel-quads per batch
  int tid = blockIdx.x * 256 + threadIdx.x;   // nb * EQ * NCHUNK
  int ep = tid % EQ;
  int tmp = tid / EQ;
  int c = tmp % NCHUNK;
  int bz = tmp / NCHUNK;
  size_t base4 = ((size_t)bz * SEQ + (size_t)c * CHUNK) * EQ + ep;
  const uint4_t* HG4 = (const uint4_t*)HG;

  float4_t asum = {0.f, 0.f, 0.f, 0.f};
  float4_t logh = {-INFINITY, -INFINITY, -INFINITY, -INFINITY};
#pragma unroll 4
  for (int t = 0; t < CHUNK; t++) {
    uint4_t u = HG4[base4 + (size_t)t * EQ];
#pragma unroll
    for (int k = 0; k < 4; k++) {
      float h = bflo2f(u[k]), g = bfhi2f(u[k]);
      float lc, lv;
      lclv_fast(h, g, lc, lv);
      asum[k] += lc;
      logh[k] = logaddexp_f(lc + logh[k], lv);
    }
  }
  size_t sidx = ((size_t)c * nbch + (size_t)bz * DIM_INNER) / 4 + ep;
  ((float4_t*)Asum)[sidx] = asum;
  ((float4_t*)Lend)[sidx] = logh;
}

__global__ __launch_bounds__(256) void scan_phase2(
    const float* __restrict__ Asum, const float* __restrict__ Lend,
    float* __restrict__ P, int nbch) {
  int ch = blockIdx.x * 256 + threadIdx.x;
  float p = -INFINITY;
#pragma unroll 8
  for (int c = 0; c < NCHUNK; c++) {
    P[(size_t)c * nbch + ch] = p;
    float a = Asum[(size_t)c * nbch + ch];
    float le = Lend[(size_t)c * nbch + ch];
    p = logaddexp_f(a + p, le);
  }
}

// Rescan with real prefix; write h = exp(log_h) as bf16 into H (8B/lane).
__global__ __launch_bounds__(256) void scan_phase3(
    const unsigned int* __restrict__ HG, const float* __restrict__ P,
    ushort_t* __restrict__ H, int nbch) {
  const int EQ = DIM_INNER / 4;
  int tid = blockIdx.x * 256 + threadIdx.x;
  int ep = tid % EQ;
  int tmp = tid / EQ;
  int c = tmp % NCHUNK;
  int bz = tmp / NCHUNK;
  size_t base4 = ((size_t)bz * SEQ + (size_t)c * CHUNK) * EQ + ep;
  const uint4_t* HG4 = (const uint4_t*)HG;
  u16x4* H4 = (u16x4*)H;

  size_t pidx = ((size_t)c * nbch + (size_t)bz * DIM_INNER) / 4 + ep;
  float4_t logh = ((const float4_t*)P)[pidx];
#pragma unroll 4
  for (int t = 0; t < CHUNK; t++) {
    uint4_t u = HG4[base4 + (size_t)t * EQ];
    u16x4 hv;
#pragma unroll
    for (int k = 0; k < 4; k++) {
      float h = bflo2f(u[k]), g = bfhi2f(u[k]);
      float lc, lv;
      lclv_fast(h, g, lc, lv);
      logh[k] = logaddexp_f(lc + logh[k], lv);
      hv[k] = f2bf(__expf(logh[k]));
    }
    H4[base4 + (size_t)t * EQ] = hv;
  }
}

// ---------------------------------------------------------------------------
// GEMM2 (m97 structure): out = H @ W_out.
// ---------------------------------------------------------------------------
__global__ __launch_bounds__(256) void gemm2(
    const ushort_t* __restrict__ Hbf, const ushort_t* __restrict__ Wot,
    float* __restrict__ OUT) {
  __shared__ __align__(16) ushort_t As[128 * 32];
  __shared__ __align__(16) ushort_t Bs[128 * 32];

  const int tid = threadIdx.x;
  const int wave = tid >> 6;
  const int lane = tid & 63;
  const int n0 = blockIdx.x * 128;
  const int m0 = blockIdx.y * 128;
  const int l15 = lane & 15;
  const int quad = lane >> 4;
  const int wr = wave >> 1, wc = wave & 1;
  const int lrow = lane >> 2;
  const int lkof = (lane & 3) * 8;

  floatx4 acc[4][4];
#pragma unroll
  for (int i = 0; i < 4; i++)
#pragma unroll
    for (int j = 0; j < 4; j++) acc[i][j] = (floatx4){0.f, 0.f, 0.f, 0.f};

  for (int k0 = 0; k0 < DIM_INNER; k0 += 32) {
    __syncthreads();
#pragma unroll
    for (int p = 0; p < 2; p++) {
      int u = wave + p * 4;
      async_copy16(Hbf + (size_t)(m0 + u * 16 + lrow) * DIM_INNER + k0 + lkof,
                   As + u * 512);
      async_copy16(Wot + (size_t)(n0 + u * 16 + lrow) * DIM_INNER + k0 + lkof,
                   Bs + u * 512);
    }
    __syncthreads();

    bf16x8 af[4], bf[4];
#pragma unroll
    for (int i = 0; i < 4; i++) {
      short8_t sa = *(const short8_t*)(As + (size_t)(wr * 64 + i * 16 + l15) * 32 + quad * 8);
      af[i] = __builtin_bit_cast(bf16x8, sa);
      short8_t sb = *(const short8_t*)(Bs + (size_t)(wc * 64 + i * 16 + l15) * 32 + quad * 8);
      bf[i] = __builtin_bit_cast(bf16x8, sb);
    }
#pragma unroll
    for (int i = 0; i < 4; i++)
#pragma unroll
      for (int j = 0; j < 4; j++)
        acc[i][j] = __builtin_amdgcn_mfma_f32_16x16x32_bf16(af[i], bf[j], acc[i][j], 0, 0, 0);
  }

#pragma unroll
  for (int i = 0; i < 4; i++)
#pragma unroll
    for (int j = 0; j < 4; j++) {
      int col = n0 + wc * 64 + j * 16 + l15;
#pragma unroll
      for (int r = 0; r < 4; r++) {
        int row = m0 + wr * 64 + i * 16 + quad * 4 + r;
        OUT[(size_t)row * DIM + col] = acc[i][j][r];
      }
    }
}

extern "C" void kernel_launch(void* const* d_in, const int* in_sizes, int n_in,
                              void* d_out, int out_size, void* d_ws, size_t ws_size,
                              hipStream_t stream) {
  const float* X = (const float*)d_in[0];     // [4,4096,1024]
  const float* Whg = (const float*)d_in[1];   // [1024,4096]
  const float* Wout = (const float*)d_in[2];  // [2048,1024]
  float* out = (float*)d_out;                 // [4,4096,1024] fp32

  ushort_t* Xbf = (ushort_t*)d_ws;
  ushort_t* Whg_t = Xbf + (size_t)MTOT * DIM;                   // [4096][1024]
  ushort_t* Wout_t = Whg_t + (size_t)(2 * DIM_INNER) * DIM;     // [1024][2048]
  char* pp = (char*)(Wout_t + (size_t)DIM * DIM_INNER);

  const size_t fixed_bytes = (size_t)MTOT * DIM * 2 +
                             (size_t)2 * DIM_INNER * DIM * 2 +
                             (size_t)DIM * DIM_INNER * 2;
  const size_t per_batch = (size_t)SEQ * DIM_INNER * 4 +
                           (size_t)SEQ * DIM_INNER * 2 +
                           3 * (size_t)DIM_INNER * NCHUNK * 4;
  int nb = 4;
  while (nb > 1 && fixed_bytes + (size_t)nb * per_batch > ws_size) nb >>= 1;
  const int npass = BATCH / nb;

  convert_f32_bf16<<<(MTOT * DIM / 4) / 256, 256, 0, stream>>>(X, Xbf);
  transpose_f32_bf16<<<dim3(2 * DIM_INNER / 32, DIM / 32), 256, 0, stream>>>(
      Whg, Whg_t, DIM, 2 * DIM_INNER);
  transpose_f32_bf16<<<dim3(DIM / 32, DIM_INNER / 32), 256, 0, stream>>>(
      Wout, Wout_t, DIM_INNER, DIM);

  for (int pass = 0; pass < npass; pass++) {
    const int b0 = pass * nb;
    const int nrows = nb * SEQ;
    const int nbch = nb * DIM_INNER;

    unsigned int* HG = (unsigned int*)pp;
    ushort_t* Hbf = (ushort_t*)(HG + (size_t)nb * SEQ * DIM_INNER);
    float* Asum = (float*)(Hbf + (size_t)nb * SEQ * DIM_INNER);
    float* Lend = Asum + (size_t)nb * DIM_INNER * NCHUNK;
    float* P = Lend + (size_t)nb * DIM_INNER * NCHUNK;

    gemm1_fused<<<dim3(DIM_INNER / 64, nrows / 128), 256, 0, stream>>>(
        Xbf + (size_t)b0 * SEQ * DIM, Whg_t, HG);
    scan_phase1<<<(nbch / 4 * NCHUNK) / 256, 256, 0, stream>>>(HG, Asum, Lend, nbch);
    scan_phase2<<<nbch / 256, 256, 0, stream>>>(Asum, Lend, P, nbch);
    scan_phase3<<<(nbch / 4 * NCHUNK) / 256, 256, 0, stream>>>(HG, P, Hbf, nbch);
    gemm2<<<dim3(DIM / 128, nrows / 128), 256, 0, stream>>>(
        Hbf, Wout_t, out + (size_t)b0 * SEQ * DIM);
  }
}

// Round 7
// 514.407 us; speedup vs baseline: 1.0622x; 1.0622x over previous
//
#include <hip/hip_runtime.h>
#include <cmath>

#define DIM 1024
#define DIM_INNER 2048
#define BATCH 4
#define SEQ 4096
#define MTOT (BATCH * SEQ)
#define CHUNK 32
#define NCHUNK (SEQ / CHUNK)        // 128 chunks per sequence

typedef __bf16 bf16x8 __attribute__((ext_vector_type(8)));
typedef short short8_t __attribute__((ext_vector_type(8)));
typedef float floatx4 __attribute__((ext_vector_type(4)));
typedef unsigned short u16x4 __attribute__((ext_vector_type(4)));
typedef unsigned int uint4_t __attribute__((ext_vector_type(4)));
typedef float float4_t __attribute__((ext_vector_type(4)));
typedef unsigned short ushort_t;

__device__ __forceinline__ unsigned short f2bf(float f) {
  unsigned int u = __builtin_bit_cast(unsigned int, f);
  u += 0x7fffu + ((u >> 16) & 1u);   // round-to-nearest-even
  return (unsigned short)(u >> 16);
}
__device__ __forceinline__ float bflo2f(unsigned int u) {
  return __builtin_bit_cast(float, u << 16);
}
__device__ __forceinline__ float bfhi2f(unsigned int u) {
  return __builtin_bit_cast(float, u & 0xffff0000u);
}

// Fast (native v_exp/v_log) log-space terms from (h, g):
//   lc = -softplus(g) ;  lv = -softplus(-g) + log_g(h) = g + lc + log_g(h)
__device__ __forceinline__ void lclv_fast(float h, float g, float& lc, float& lv) {
  float eg = __expf(-fabsf(g));
  float sp = fmaxf(g, 0.f) + __logf(1.f + eg);
  lc = -sp;
  float eh = __expf(h);
  float t  = (h >= 0.f) ? (h + 0.5f) : (1.f + eh);
  float lt = __logf(t);
  float lg = (h >= 0.f) ? lt : (h - lt);
  lv = g + lc + lg;
}
// a may be -inf; b finite
__device__ __forceinline__ float logaddexp_f(float a, float b) {
  float m = fmaxf(a, b);
  return m + __logf(1.f + __expf(-fabsf(a - b)));
}

// async 16B/lane global->LDS; dest = wave-uniform base + lane*16
__device__ __forceinline__ void async_copy16(const ushort_t* g, ushort_t* l) {
  __builtin_amdgcn_global_load_lds(
      (const __attribute__((address_space(1))) void*)g,
      (__attribute__((address_space(3))) void*)l, 16, 0, 0);
}

// ---------------------------------------------------------------------------
// One-time input conversions
// ---------------------------------------------------------------------------
__global__ __launch_bounds__(256) void convert_f32_bf16(
    const float* __restrict__ src, ushort_t* __restrict__ dst) {
  int i = blockIdx.x * 256 + threadIdx.x;   // one float4 per thread
  float4 v = ((const float4*)src)[i];
  u16x4 o = {f2bf(v.x), f2bf(v.y), f2bf(v.z), f2bf(v.w)};
  ((u16x4*)dst)[i] = o;
}

// dst[n][k] = bf16(src[k][n]); src is [K][N] fp32
__global__ __launch_bounds__(256) void transpose_f32_bf16(
    const float* __restrict__ src, ushort_t* __restrict__ dst, int K, int N) {
  __shared__ float tile[32][33];
  int tx = threadIdx.x & 31, ty = threadIdx.x >> 5;   // 32 x 8
  int n0 = blockIdx.x * 32, k0 = blockIdx.y * 32;
#pragma unroll
  for (int i = 0; i < 4; i++) {
    int k = ty + i * 8;
    tile[k][tx] = src[(size_t)(k0 + k) * N + n0 + tx];
  }
  __syncthreads();
#pragma unroll
  for (int i = 0; i < 4; i++) {
    int r = ty + i * 8;
    dst[(size_t)(n0 + r) * K + k0 + tx] = f2bf(tile[tx][r]);
  }
}

// ---------------------------------------------------------------------------
// GEMM1 fused: per block a 128x64 h-tile + 128x64 g-tile (shared A tile).
// Epilogue computes (lc,lv) with fast math from fp32 accumulators and packs
// them as 2xbf16 -> LCLV.
// ---------------------------------------------------------------------------
__global__ __launch_bounds__(256) void gemm1_fused(
    const ushort_t* __restrict__ Xbf, const ushort_t* __restrict__ Wt,
    unsigned int* __restrict__ LCLV) {
  __shared__ __align__(16) ushort_t As[128 * 32];   // 8 KB
  __shared__ __align__(16) ushort_t Bh[64 * 32];    // 4 KB
  __shared__ __align__(16) ushort_t Bg[64 * 32];    // 4 KB

  const int tid = threadIdx.x;
  const int wave = tid >> 6;
  const int lane = tid & 63;
  const int n0 = blockIdx.x * 64;
  const int m0 = blockIdx.y * 128;
  const int l15 = lane & 15;
  const int quad = lane >> 4;
  const int wr = wave >> 1, wc = wave & 1;
  const int lrow = lane >> 2;
  const int lkof = (lane & 3) * 8;

  floatx4 acch[4][2], accg[4][2];
#pragma unroll
  for (int i = 0; i < 4; i++)
#pragma unroll
    for (int j = 0; j < 2; j++) {
      acch[i][j] = (floatx4){0.f, 0.f, 0.f, 0.f};
      accg[i][j] = (floatx4){0.f, 0.f, 0.f, 0.f};
    }

  for (int k0 = 0; k0 < DIM; k0 += 32) {
    __syncthreads();
    async_copy16(Xbf + (size_t)(m0 + wave * 16 + lrow) * DIM + k0 + lkof,
                 As + wave * 512);
    async_copy16(Xbf + (size_t)(m0 + (wave + 4) * 16 + lrow) * DIM + k0 + lkof,
                 As + (wave + 4) * 512);
    async_copy16(Wt + (size_t)(n0 + wave * 16 + lrow) * DIM + k0 + lkof,
                 Bh + wave * 512);
    async_copy16(Wt + (size_t)(n0 + DIM_INNER + wave * 16 + lrow) * DIM + k0 + lkof,
                 Bg + wave * 512);
    __syncthreads();

    bf16x8 af[4], bhf[2], bgf[2];
#pragma unroll
    for (int i = 0; i < 4; i++) {
      short8_t sa = *(const short8_t*)(As + (size_t)(wr * 64 + i * 16 + l15) * 32 + quad * 8);
      af[i] = __builtin_bit_cast(bf16x8, sa);
    }
#pragma unroll
    for (int j = 0; j < 2; j++) {
      short8_t sh = *(const short8_t*)(Bh + (size_t)(wc * 32 + j * 16 + l15) * 32 + quad * 8);
      bhf[j] = __builtin_bit_cast(bf16x8, sh);
      short8_t sg = *(const short8_t*)(Bg + (size_t)(wc * 32 + j * 16 + l15) * 32 + quad * 8);
      bgf[j] = __builtin_bit_cast(bf16x8, sg);
    }
#pragma unroll
    for (int i = 0; i < 4; i++)
#pragma unroll
      for (int j = 0; j < 2; j++) {
        acch[i][j] = __builtin_amdgcn_mfma_f32_16x16x32_bf16(af[i], bhf[j], acch[i][j], 0, 0, 0);
        accg[i][j] = __builtin_amdgcn_mfma_f32_16x16x32_bf16(af[i], bgf[j], accg[i][j], 0, 0, 0);
      }
  }

#pragma unroll
  for (int i = 0; i < 4; i++)
#pragma unroll
    for (int j = 0; j < 2; j++) {
      int col = n0 + wc * 32 + j * 16 + l15;
#pragma unroll
      for (int r = 0; r < 4; r++) {
        int row = m0 + wr * 64 + i * 16 + quad * 4 + r;
        float lc, lv;
        lclv_fast(acch[i][j][r], accg[i][j][r], lc, lv);
        unsigned int pk = ((unsigned int)f2bf(lv) << 16) | (unsigned int)f2bf(lc);
        LCLV[(size_t)row * DIM_INNER + col] = pk;
      }
    }
}

// ---------------------------------------------------------------------------
// Chunked log-space scan, 4 channels/thread, CHUNK=32 (262k threads @ nb=4)
// ---------------------------------------------------------------------------
__global__ __launch_bounds__(256) void scan_phase1(
    const unsigned int* __restrict__ LCLV,
    float* __restrict__ Asum, float* __restrict__ Lend, int nbch) {
  const int EQ = DIM_INNER / 4;               // 512 channel-quads per batch
  int tid = blockIdx.x * 256 + threadIdx.x;   // nb * EQ * NCHUNK
  int ep = tid % EQ;
  int tmp = tid / EQ;
  int c = tmp % NCHUNK;
  int bz = tmp / NCHUNK;
  size_t base4 = ((size_t)bz * SEQ + (size_t)c * CHUNK) * EQ + ep;
  const uint4_t* L4 = (const uint4_t*)LCLV;

  float4_t asum = {0.f, 0.f, 0.f, 0.f};
  float4_t logh = {-INFINITY, -INFINITY, -INFINITY, -INFINITY};
#pragma unroll 4
  for (int t = 0; t < CHUNK; t++) {
    uint4_t u = L4[base4 + (size_t)t * EQ];
#pragma unroll
    for (int k = 0; k < 4; k++) {
      float lc = bflo2f(u[k]), lv = bfhi2f(u[k]);
      asum[k] += lc;
      logh[k] = logaddexp_f(lc + logh[k], lv);
    }
  }
  size_t sidx = ((size_t)c * nbch + (size_t)bz * DIM_INNER) / 4 + ep;
  ((float4_t*)Asum)[sidx] = asum;
  ((float4_t*)Lend)[sidx] = logh;
}

// In-place: Asum[c][ch] -> P[c][ch] (prefix BEFORE chunk c)
__global__ __launch_bounds__(256) void scan_phase2(
    float* Asum, const float* __restrict__ Lend, int nbch) {
  int ch = blockIdx.x * 256 + threadIdx.x;
  float p = -INFINITY;
  for (int c = 0; c < NCHUNK; c++) {
    float a = Asum[(size_t)c * nbch + ch];
    float le = Lend[(size_t)c * nbch + ch];
    Asum[(size_t)c * nbch + ch] = p;
    p = logaddexp_f(a + p, le);
  }
}

// Rescan with real prefix; write h = exp(log_h) as bf16 into H (8B/lane).
__global__ __launch_bounds__(256) void scan_phase3(
    const unsigned int* __restrict__ LCLV, const float* __restrict__ P,
    ushort_t* __restrict__ H, int nbch) {
  const int EQ = DIM_INNER / 4;
  int tid = blockIdx.x * 256 + threadIdx.x;
  int ep = tid % EQ;
  int tmp = tid / EQ;
  int c = tmp % NCHUNK;
  int bz = tmp / NCHUNK;
  size_t base4 = ((size_t)bz * SEQ + (size_t)c * CHUNK) * EQ + ep;
  const uint4_t* L4 = (const uint4_t*)LCLV;
  u16x4* H4 = (u16x4*)H;

  size_t pidx = ((size_t)c * nbch + (size_t)bz * DIM_INNER) / 4 + ep;
  float4_t logh = ((const float4_t*)P)[pidx];
#pragma unroll 4
  for (int t = 0; t < CHUNK; t++) {
    uint4_t u = L4[base4 + (size_t)t * EQ];
    u16x4 hv;
#pragma unroll
    for (int k = 0; k < 4; k++) {
      float lc = bflo2f(u[k]), lv = bfhi2f(u[k]);
      logh[k] = logaddexp_f(lc + logh[k], lv);
      hv[k] = f2bf(__expf(logh[k]));
    }
    H4[base4 + (size_t)t * EQ] = hv;
  }
}

// ---------------------------------------------------------------------------
// GEMM2 (m97 structure): out = H @ W_out.
// ---------------------------------------------------------------------------
__global__ __launch_bounds__(256) void gemm2(
    const ushort_t* __restrict__ Hbf, const ushort_t* __restrict__ Wot,
    float* __restrict__ OUT) {
  __shared__ __align__(16) ushort_t As[128 * 32];
  __shared__ __align__(16) ushort_t Bs[128 * 32];

  const int tid = threadIdx.x;
  const int wave = tid >> 6;
  const int lane = tid & 63;
  const int n0 = blockIdx.x * 128;
  const int m0 = blockIdx.y * 128;
  const int l15 = lane & 15;
  const int quad = lane >> 4;
  const int wr = wave >> 1, wc = wave & 1;
  const int lrow = lane >> 2;
  const int lkof = (lane & 3) * 8;

  floatx4 acc[4][4];
#pragma unroll
  for (int i = 0; i < 4; i++)
#pragma unroll
    for (int j = 0; j < 4; j++) acc[i][j] = (floatx4){0.f, 0.f, 0.f, 0.f};

  for (int k0 = 0; k0 < DIM_INNER; k0 += 32) {
    __syncthreads();
#pragma unroll
    for (int p = 0; p < 2; p++) {
      int u = wave + p * 4;
      async_copy16(Hbf + (size_t)(m0 + u * 16 + lrow) * DIM_INNER + k0 + lkof,
                   As + u * 512);
      async_copy16(Wot + (size_t)(n0 + u * 16 + lrow) * DIM_INNER + k0 + lkof,
                   Bs + u * 512);
    }
    __syncthreads();

    bf16x8 af[4], bf[4];
#pragma unroll
    for (int i = 0; i < 4; i++) {
      short8_t sa = *(const short8_t*)(As + (size_t)(wr * 64 + i * 16 + l15) * 32 + quad * 8);
      af[i] = __builtin_bit_cast(bf16x8, sa);
      short8_t sb = *(const short8_t*)(Bs + (size_t)(wc * 64 + i * 16 + l15) * 32 + quad * 8);
      bf[i] = __builtin_bit_cast(bf16x8, sb);
    }
#pragma unroll
    for (int i = 0; i < 4; i++)
#pragma unroll
      for (int j = 0; j < 4; j++)
        acc[i][j] = __builtin_amdgcn_mfma_f32_16x16x32_bf16(af[i], bf[j], acc[i][j], 0, 0, 0);
  }

#pragma unroll
  for (int i = 0; i < 4; i++)
#pragma unroll
    for (int j = 0; j < 4; j++) {
      int col = n0 + wc * 64 + j * 16 + l15;
#pragma unroll
      for (int r = 0; r < 4; r++) {
        int row = m0 + wr * 64 + i * 16 + quad * 4 + r;
        OUT[(size_t)row * DIM + col] = acc[i][j][r];
      }
    }
}

extern "C" void kernel_launch(void* const* d_in, const int* in_sizes, int n_in,
                              void* d_out, int out_size, void* d_ws, size_t ws_size,
                              hipStream_t stream) {
  const float* X = (const float*)d_in[0];     // [4,4096,1024]
  const float* Whg = (const float*)d_in[1];   // [1024,4096]
  const float* Wout = (const float*)d_in[2];  // [2048,1024]
  float* out = (float*)d_out;                 // [4,4096,1024] fp32

  ushort_t* Xbf = (ushort_t*)d_ws;
  ushort_t* Whg_t = Xbf + (size_t)MTOT * DIM;                   // [4096][1024]
  ushort_t* Wout_t = Whg_t + (size_t)(2 * DIM_INNER) * DIM;     // [1024][2048]
  char* pp = (char*)(Wout_t + (size_t)DIM * DIM_INNER);

  const size_t fixed_bytes = (size_t)MTOT * DIM * 2 +
                             (size_t)2 * DIM_INNER * DIM * 2 +
                             (size_t)DIM * DIM_INNER * 2;
  // per batch: LCLV 4B + H 2B per elem + 2 summaries
  const size_t per_batch = (size_t)SEQ * DIM_INNER * 4 +
                           (size_t)SEQ * DIM_INNER * 2 +
                           2 * (size_t)DIM_INNER * NCHUNK * 4;
  int nb = 4;
  while (nb > 1 && fixed_bytes + (size_t)nb * per_batch > ws_size) nb >>= 1;
  const int npass = BATCH / nb;

  convert_f32_bf16<<<(MTOT * DIM / 4) / 256, 256, 0, stream>>>(X, Xbf);
  transpose_f32_bf16<<<dim3(2 * DIM_INNER / 32, DIM / 32), 256, 0, stream>>>(
      Whg, Whg_t, DIM, 2 * DIM_INNER);
  transpose_f32_bf16<<<dim3(DIM / 32, DIM_INNER / 32), 256, 0, stream>>>(
      Wout, Wout_t, DIM_INNER, DIM);

  for (int pass = 0; pass < npass; pass++) {
    const int b0 = pass * nb;
    const int nrows = nb * SEQ;
    const int nbch = nb * DIM_INNER;

    unsigned int* LCLV = (unsigned int*)pp;
    ushort_t* Hbf = (ushort_t*)(LCLV + (size_t)nb * SEQ * DIM_INNER);
    float* Asum = (float*)(Hbf + (size_t)nb * SEQ * DIM_INNER);
    float* Lend = Asum + (size_t)nb * DIM_INNER * NCHUNK;

    gemm1_fused<<<dim3(DIM_INNER / 64, nrows / 128), 256, 0, stream>>>(
        Xbf + (size_t)b0 * SEQ * DIM, Whg_t, LCLV);
    scan_phase1<<<(nbch / 4 * NCHUNK) / 256, 256, 0, stream>>>(LCLV, Asum, Lend, nbch);
    scan_phase2<<<nbch / 256, 256, 0, stream>>>(Asum, Lend, nbch);
    scan_phase3<<<(nbch / 4 * NCHUNK) / 256, 256, 0, stream>>>(LCLV, Asum, Hbf, nbch);
    gemm2<<<dim3(DIM / 128, nrows / 128), 256, 0, stream>>>(
        Hbf, Wout_t, out + (size_t)b0 * SEQ * DIM);
  }
}